// Round 4
// baseline (530.106 us; speedup 1.0000x reference)
//
#include <hip/hip_runtime.h>

#define PAD   4
#define DD    9
#define ND    81
#define CCH   256
#define HH_   128
#define WW_   224
#define TH    8
#define TW    32
#define NTILES 448               // 7 wtiles * 16 htiles * 4 batch
#define PLANE  (HH_*WW_)

#define COMP(F,L,M,R) do {                                              \
    const float s_[12] = {L.x,L.y,L.z,L.w, M.x,M.y,M.z,M.w,             \
                          R.x,R.y,R.z,R.w};                             \
    const float f_[4]  = {F.x,F.y,F.z,F.w};                             \
    _Pragma("unroll")                                                   \
    for (int dx_ = 0; dx_ < DD; ++dx_)                                  \
        _Pragma("unroll")                                               \
        for (int px_ = 0; px_ < 4; ++px_)                               \
            acc[dx_][px_] += f_[px_] * s_[dx_ + px_];                   \
} while (0)

__global__ __launch_bounds__(64)
void corr_kernel(const float* __restrict__ first,
                 const float* __restrict__ second,
                 const float* __restrict__ zws,    // >=256 B of zeros
                 float* __restrict__ out)
{
    const int bx   = blockIdx.x;
    const int tile = bx % NTILES;
    const int dy   = bx / NTILES;
    const int wt   = tile % 7;
    const int ht   = (tile / 7) % 16;
    const int b    = tile / 112;
    const int w0   = wt * TW, h0 = ht * TH;

    const int lane = threadIdx.x;
    const int wq   = lane & 7;
    const int hh   = lane >> 3;
    const int h = h0 + hh;
    const int w = w0 + 4 * wq;

    const int srow = h + dy - PAD;
    const bool vr  = (srow >= 0) && (srow < HH_);

    const size_t plane = PLANE;
    const float* fbase  = first  + (size_t)b * CCH * plane;
    const float* sbase  = second + (size_t)b * CCH * plane;
    const float* srbase = sbase + (size_t)(vr ? srow : 0) * WW_;

    // 12-float window = 3 aligned quads at w-4, w, w+4; branchless OOB via
    // redirect-to-zeros pointer with zero channel stride.
    const bool vL = vr && (w - 4 >= 0);
    const bool vR = vr && (w + 8 <= WW_);
    const float* fp = fbase + (size_t)h * WW_ + w;
    const float* pL = vL ? (srbase + (w - 4)) : zws;
    const float* pM = vr ? (srbase + w)       : zws;
    const float* pR = vR ? (srbase + (w + 4)) : zws;
    const size_t iL = vL ? plane : 0;
    const size_t iM = vr ? plane : 0;
    const size_t iR = vR ? plane : 0;

    float acc[DD][4];
    #pragma unroll
    for (int dx = 0; dx < DD; ++dx) { acc[dx][0]=0.f; acc[dx][1]=0.f; acc[dx][2]=0.f; acc[dx][3]=0.f; }

    // software pipeline, prefetch depth 2
    float4 fA = *(const float4*)fp; fp += plane;
    float4 lA = *(const float4*)pL; pL += iL;
    float4 mA = *(const float4*)pM; pM += iM;
    float4 rA = *(const float4*)pR; pR += iR;
    float4 fB = *(const float4*)fp; fp += plane;
    float4 lB = *(const float4*)pL; pL += iL;
    float4 mB = *(const float4*)pM; pM += iM;
    float4 rB = *(const float4*)pR; pR += iR;

    for (int c = 0; c < CCH - 2; c += 2) {
        float4 fC = *(const float4*)fp; fp += plane;
        float4 lC = *(const float4*)pL; pL += iL;
        float4 mC = *(const float4*)pM; pM += iM;
        float4 rC = *(const float4*)pR; pR += iR;
        float4 fD = *(const float4*)fp; fp += plane;
        float4 lD = *(const float4*)pL; pL += iL;
        float4 mD = *(const float4*)pM; pM += iM;
        float4 rD = *(const float4*)pR; pR += iR;

        COMP(fA, lA, mA, rA);
        COMP(fB, lB, mB, rB);

        fA = fC; lA = lC; mA = mC; rA = rC;
        fB = fD; lB = lD; mB = mD; rB = rD;
    }
    COMP(fA, lA, mA, rA);
    COMP(fB, lB, mB, rB);

    const float inv = 1.0f / (float)CCH;
    #pragma unroll
    for (int dx = 0; dx < DD; ++dx) {
        const int d = dy * DD + dx;
        float4 o = make_float4(acc[dx][0]*inv, acc[dx][1]*inv,
                               acc[dx][2]*inv, acc[dx][3]*inv);
        *(float4*)&out[(((size_t)b * ND + d) * HH_ + h) * WW_ + w] = o;
    }
}

extern "C" void kernel_launch(void* const* d_in, const int* in_sizes, int n_in,
                              void* d_out, int out_size, void* d_ws, size_t ws_size,
                              hipStream_t stream) {
    const float* first  = (const float*)d_in[0];
    const float* second = (const float*)d_in[1];
    float* out = (float*)d_out;
    hipMemsetAsync(d_ws, 0, 256, stream);   // zero pad for OOB redirection
    dim3 grid(NTILES * DD);                 // 4032 single-wave blocks
    dim3 block(64);
    corr_kernel<<<grid, block, 0, stream>>>(first, second, (const float*)d_ws, out);
}